// Round 16
// baseline (513.858 us; speedup 1.0000x reference)
//
#include <hip/hip_runtime.h>
#include <hip/hip_bf16.h>
#include <float.h>
#include <math.h>

typedef float f32x4 __attribute__((ext_vector_type(4)));
typedef short short8 __attribute__((ext_vector_type(8)));
typedef unsigned int uint32;

#define NB 4
#define SQ 4096
#define DM 4096
#define DH 128
#define LOG2E 1.44269504088896f
#define SCALE 0.0883883476483184f   // 1/sqrt(128)
#define SCL2 (SCALE * LOG2E)        // fold into log2 domain

__device__ __forceinline__ unsigned short f2bf(float f) {
  union { float f; unsigned u; } x; x.f = f;
  unsigned r = x.u + 0x7FFFu + ((x.u >> 16) & 1u);
  return (unsigned short)(r >> 16);
}

__device__ __forceinline__ uint2 cvt4(float4 f) {
  uint2 u;
  asm("v_cvt_pk_bf16_f32 %0, %1, %2" : "=v"(u.x) : "v"(f.x), "v"(f.y));
  asm("v_cvt_pk_bf16_f32 %0, %1, %2" : "=v"(u.y) : "v"(f.z), "v"(f.w));
  return u;
}

__device__ __forceinline__ short8 pack8(f32x4 u, f32x4 v) {
  uint32 r0, r1, r2, r3;
  asm("v_cvt_pk_bf16_f32 %0, %1, %2" : "=v"(r0) : "v"(u[0]), "v"(u[1]));
  asm("v_cvt_pk_bf16_f32 %0, %1, %2" : "=v"(r1) : "v"(u[2]), "v"(u[3]));
  asm("v_cvt_pk_bf16_f32 %0, %1, %2" : "=v"(r2) : "v"(v[0]), "v"(v[1]));
  asm("v_cvt_pk_bf16_f32 %0, %1, %2" : "=v"(r3) : "v"(v[2]), "v"(v[3]));
  union { uint32 w[4]; short8 s; } z;
  z.w[0] = r0; z.w[1] = r1; z.w[2] = r2; z.w[3] = r3;
  return z.s;
}

#define GLD16(g, l) __builtin_amdgcn_global_load_lds( \
    (const __attribute__((address_space(1))) void*)(g), \
    (__attribute__((address_space(3))) void*)(l), 16, 0, 0)

// ---------------- kernel 1: pack weights (bf16) + bias (f32) ----------------
__global__ void cast_w_kernel(const float* __restrict__ wq, const float* __restrict__ wk,
                              const float* __restrict__ wv, const float* __restrict__ bq,
                              const float* __restrict__ bk, const float* __restrict__ bv,
                              unsigned short* __restrict__ wb, float* __restrict__ biasws) {
  int t = blockIdx.x * 256 + threadIdx.x;  // 0..196607, each handles 8 elems
  int base = t * 8;
  int n = base >> 12;       // output row 0..383 (q:0-127, k:128-255, v:256-383)
  int d = base & 4095;
  const float* src = (n < 128) ? (wq + (size_t)n * DM)
                   : (n < 256) ? (wk + (size_t)(n - 128) * DM)
                               : (wv + (size_t)(n - 256) * DM);
  float4 f0 = *(const float4*)(src + d);
  float4 f1 = *(const float4*)(src + d + 4);
  short8 v;
  v[0] = (short)f2bf(f0.x); v[1] = (short)f2bf(f0.y);
  v[2] = (short)f2bf(f0.z); v[3] = (short)f2bf(f0.w);
  v[4] = (short)f2bf(f1.x); v[5] = (short)f2bf(f1.y);
  v[6] = (short)f2bf(f1.z); v[7] = (short)f2bf(f1.w);
  *(short8*)(wb + base) = v;
  if (t < 384) biasws[t] = (t < 128) ? bq[t] : (t < 256) ? bk[t - 128] : bv[t - 256];
}

// ---------------- kernel 2: fused QKV GEMM + bias + RoPE (+ V^T store) ------
// BARRIER-FREE dataflow GEMM, retry of R15 with both NaN suspects removed:
//   (a) reissue index clamped in-bounds: kn = ((t+3)&127)*32 (t=125's dead
//       slot reloads k=0 harmlessly; R15 read 240B past x/wb -> corruption)
//   (b) __launch_bounds__(128,2): VGPR cap 256 (R15's (128,3) capped at ~168
//       < live state ~175 -> spills of in-flight load destinations)
// Wave-tile 64x32 (acc 4x2), K-step 32, TRUE depth-3 slot rotation (slot t%3
// consumed at t, reissued for t+3 -> ages 2 full iterations). No LDS, no
// barriers. 2 blocks/CU = 8 waves/CU. Same-m-tile n-slices adjacent in bid ->
// same XCD -> x L2-shared (R6 measured FETCH 1.15x ideal at this geometry).
struct ABuf { f32x4 r[8]; };    // 4 m-frags x 8 f32
struct BBuf { short8 b[2]; };   // 2 n-frags

__global__ __launch_bounds__(128, 2) void gemm_qkv_rope(
    const float* __restrict__ x, const unsigned short* __restrict__ wb,
    const float* __restrict__ biasws, const float* __restrict__ sing,
    const float* __restrict__ cosg, unsigned short* __restrict__ qb,
    unsigned short* __restrict__ kb, unsigned short* __restrict__ vt) {
  const int tid = threadIdx.x;
  const int l = tid & 63, w = tid >> 6;
  const int l15 = l & 15, lg = l >> 4;

  // 192 blocks per XCD = 16 m-tiles x 12 n-slices (adjacent -> x L2-shared)
  const int bid = blockIdx.x;
  const int xcd = bid & 7, q = bid >> 3;
  const int mloc = q / 12, nsl = q - mloc * 12;
  const int m0 = (xcd * 16 + mloc) * 128 + w * 64;   // wave's 64 rows
  const int n0 = nsl * 32;
  const int head = nsl >> 2;                          // block-uniform

  const float* xsrc = x + (size_t)(m0 + l15) * DM + lg * 8;
  const unsigned short* bsrc = wb + (size_t)(n0 + l15) * DM + lg * 8;

  f32x4 acc[4][2] = {};
  ABuf A0, A1, A2;
  BBuf B0, B1, B2;

  auto ldA = [&](ABuf& A, int k) {
#pragma unroll
    for (int mi = 0; mi < 4; ++mi) {
      A.r[2 * mi]     = *(const f32x4*)(xsrc + (size_t)mi * 16 * DM + k);
      A.r[2 * mi + 1] = *(const f32x4*)(xsrc + (size_t)mi * 16 * DM + k + 4);
    }
  };
  auto ldB = [&](BBuf& B, int k) {
    B.b[0] = *(const short8*)(bsrc + k);
    B.b[1] = *(const short8*)(bsrc + (size_t)16 * DM + k);
  };

  ldA(A0, 0);  ldB(B0, 0);
  ldA(A1, 32); ldB(B1, 32);
  ldA(A2, 64); ldB(B2, 64);

  // one step: consume slot (aged 2 iters), reissue slot for t+3, 8 MFMA
  auto body = [&](ABuf& A, BBuf& B, int t, bool re) {
    short8 af[4];
#pragma unroll
    for (int mi = 0; mi < 4; ++mi) af[mi] = pack8(A.r[2 * mi], A.r[2 * mi + 1]);
    short8 b0 = B.b[0], b1 = B.b[1];
    if (re) {
      const int kn = ((t + 3) & 127) * 32;   // in-bounds clamp (t=125 -> k=0, dead slot)
      ldA(A, kn);
      ldB(B, kn);
    }
#pragma unroll
    for (int mi = 0; mi < 4; ++mi) {
      acc[mi][0] = __builtin_amdgcn_mfma_f32_16x16x32_bf16(af[mi], b0, acc[mi][0], 0, 0, 0);
      acc[mi][1] = __builtin_amdgcn_mfma_f32_16x16x32_bf16(af[mi], b1, acc[mi][1], 0, 0, 0);
    }
  };

#pragma unroll 1
  for (int tt = 0; tt < 42; ++tt) {
    const int t = tt * 3;
    body(A0, B0, t, true);
    body(A1, B1, t + 1, true);
    body(A2, B2, t + 2, true);
  }
  body(A0, B0, 126, false);
  body(A1, B1, 127, false);

  // epilogue: bias (+ RoPE for q,k -- block-uniform), store bf16
  if (head == 2) {
    // V: store TRANSPOSED. Frag holds 4 consecutive seq-rows for one h.
    unsigned short* vtb = vt + (size_t)(m0 >> 12) * DH * SQ;
    const int srow = m0 & (SQ - 1);
#pragma unroll
    for (int mi = 0; mi < 4; ++mi)
#pragma unroll
      for (int ni = 0; ni < 2; ++ni) {
        int h = (n0 & 127) + ni * 16 + l15;
        float bias = biasws[256 + h];
        f32x4 a = acc[mi][ni];
        float4 f;
        f.x = a[0] + bias; f.y = a[1] + bias; f.z = a[2] + bias; f.w = a[3] + bias;
        *(uint2*)&vtb[(size_t)h * SQ + srow + mi * 16 + lg * 4] = cvt4(f);
      }
  } else {
    unsigned short* dst = (head == 0) ? qb : kb;
#pragma unroll
    for (int mi = 0; mi < 4; ++mi)
#pragma unroll
      for (int ni = 0; ni < 2; ++ni) {
        int h = (n0 & 127) + ni * 16 + l15;
        float bias = biasws[head * 128 + h];
        f32x4 a = acc[mi][ni];
#pragma unroll
        for (int j2 = 0; j2 < 4; ++j2) {
          int row = m0 + mi * 16 + lg * 4 + j2;
          float val = a[j2] + bias;
          // reference RoPE: out[h] = v[h]*cos[h] + v_sw[h]*sin[h],
          // v_sw[2i] = v_sw[2i+1] = v[2i+1] (odd element, repeated)
          int s = row & (SQ - 1);
          float cs = cosg[s * DH + h];
          float sn = sing[s * DH + h];
          float pr = __shfl_xor(val, 1, 64);      // partner col h^1 (same row)
          float sw = (l & 1) ? val : pr;          // odd h: self; even h: h+1
          val = val * cs + sw * sn;
          dst[(size_t)row * DH + h] = f2bf(val);
        }
      }
  }
}

// ---------------- kernel 3: causal flash attention, QBLK=32 ----------------
// (R14, unchanged -- measured ~20us)
__global__ __launch_bounds__(256) void attn_kernel(
    const unsigned short* __restrict__ qb, const unsigned short* __restrict__ kb,
    const unsigned short* __restrict__ vt, float* __restrict__ out) {
  __shared__ __align__(16) short KV[4 * 8192];        // 64 KB
  __shared__ __align__(16) short Plds4[4 * 1152];     // 9 KB
  __shared__ __align__(16) float Mlds[64];
  __shared__ __align__(16) float Llds[64];
  __shared__ __align__(16) float Clds[64];
  const int tid = threadIdx.x;
  const int w = tid >> 6, l = tid & 63;
  const int qsub = w >> 1, ksp = w & 1;
  const int l15 = l & 15, lg = l >> 4;

  const int bi = blockIdx.x;
  const int slot = bi & 7, p5 = slot & 1, batch = slot >> 1;
  const int a = bi >> 3;  // 0..63
  const int t = (a & 1) ? (127 - p5 * 32 - (a >> 1)) : (p5 * 32 + (a >> 1));
  const int q0 = t * 32;
  const int qb0 = q0 + qsub * 16;
  const size_t bbase = (size_t)batch * SQ;
  const unsigned short* Kb = kb + bbase * DH;
  const unsigned short* Vtb = vt + (size_t)batch * DH * SQ;

  short* Kp = KV + ksp * 8192;            // [64][128] bf16, chunk^(row&15)
  short* Vp = KV + 16384 + ksp * 8192;    // [128][64] bf16, chunk^(row&7)
  short* Pw = Plds4 + w * 1152;           // [16][72]

  const int ti = qsub * 64 + l;
  const int krow_ = ti >> 4, kc_ = ti & 15;
  const int vrow_ = ti >> 3, vc_ = ti & 7;

  short8 qf[4];
  {
    const unsigned short* qp = qb + (bbase + qb0 + l15) * DH + lg * 8;
#pragma unroll
    for (int kcd = 0; kcd < 4; ++kcd) qf[kcd] = *(const short8*)(qp + kcd * 32);
  }

  const int nsteps = (q0 + 32 + 63) >> 6;
  const int nsteps_w = (qb0 + 16 + 63) >> 6;
  const int max_nit = (nsteps + 1) >> 1;

  float m_r = -INFINITY, l_r = 0.f;
  f32x4 o[8] = {};

  for (int it = 0; it < max_nit; ++it) {
    const int st = it * 2 + ksp;
    const int kv0 = st * 64;
    if (st < nsteps) {
#pragma unroll
      for (int i = 0; i < 8; ++i) {
        int row = i * 8 + krow_;
        GLD16(Kb + (size_t)(kv0 + row) * DH + ((kc_ ^ (row & 15)) * 8),
              (char*)Kp + (i * 128 + ti) * 16);
      }
#pragma unroll
      for (int i = 0; i < 8; ++i) {
        int row = i * 16 + vrow_;
        GLD16(Vtb + (size_t)row * SQ + kv0 + ((vc_ ^ (row & 7)) * 8),
              (char*)Vp + (i * 128 + ti) * 16);
      }
    }
    asm volatile("s_waitcnt vmcnt(0)" ::: "memory");
    __builtin_amdgcn_s_barrier();

    if (st < nsteps_w) {
      f32x4 sf[4] = {};
      __builtin_amdgcn_s_setprio(1);
#pragma unroll
      for (int kcd = 0; kcd < 4; ++kcd)
#pragma unroll
        for (int ni = 0; ni < 4; ++ni) {
          int r = ni * 16 + l15;
          short8 kf = *(short8*)&Kp[r * 128 + (((kcd * 4 + lg) ^ (r & 15)) * 8)];
          sf[ni] = __builtin_amdgcn_mfma_f32_16x16x32_bf16(kf, qf[kcd], sf[ni], 0, 0, 0);
        }
      __builtin_amdgcn_s_setprio(0);

      float s[4][4];
      if (st == nsteps_w - 1) {
#pragma unroll
        for (int ni = 0; ni < 4; ++ni)
#pragma unroll
          for (int j = 0; j < 4; ++j) {
            float v = sf[ni][j] * SCL2;
            if (kv0 + ni * 16 + lg * 4 + j > qb0 + l15) v = -FLT_MAX;
            s[ni][j] = v;
          }
      } else {
#pragma unroll
        for (int ni = 0; ni < 4; ++ni)
#pragma unroll
          for (int j = 0; j < 4; ++j) s[ni][j] = sf[ni][j] * SCL2;
      }

      float tmx = s[0][0];
#pragma unroll
      for (int ni = 0; ni < 4; ++ni)
#pragma unroll
        for (int j = 0; j < 4; ++j) tmx = fmaxf(tmx, s[ni][j]);
      tmx = fmaxf(tmx, __shfl_xor(tmx, 16, 64));
      tmx = fmaxf(tmx, __shfl_xor(tmx, 32, 64));

      if (__any(tmx > m_r + 8.0f)) {
        float mnew = fmaxf(m_r, tmx);
        float corr = exp2f(m_r - mnew);
        if (l < 16) Clds[w * 16 + l] = corr;
        l_r *= corr; m_r = mnew;
        f32x4 c4 = *(f32x4*)&Clds[w * 16 + lg * 4];
#pragma unroll
        for (int nd = 0; nd < 8; ++nd)
#pragma unroll
          for (int j = 0; j < 4; ++j) o[nd][j] *= c4[j];
      }

      float rs = 0.f;
      float pp[4][4];
#pragma unroll
      for (int ni = 0; ni < 4; ++ni)
#pragma unroll
        for (int j = 0; j < 4; ++j) {
          pp[ni][j] = exp2f(s[ni][j] - m_r);
          rs += pp[ni][j];
        }
      rs += __shfl_xor(rs, 16, 64);
      rs += __shfl_xor(rs, 32, 64);
      l_r += rs;

#pragma unroll
      for (int ni = 0; ni < 4; ++ni) {
        uint32 lo, hi;
        asm volatile("v_cvt_pk_bf16_f32 %0, %1, %2" : "=v"(lo) : "v"(pp[ni][0]), "v"(pp[ni][1]));
        asm volatile("v_cvt_pk_bf16_f32 %0, %1, %2" : "=v"(hi) : "v"(pp[ni][2]), "v"(pp[ni][3]));
        uint2 u; u.x = lo; u.y = hi;
        *(uint2*)&Pw[l15 * 72 + ni * 16 + lg * 4] = u;
      }
      short8 pa0 = *(short8*)&Pw[l15 * 72 + lg * 8];
      short8 pa1 = *(short8*)&Pw[l15 * 72 + 32 + lg * 8];

      __builtin_amdgcn_s_setprio(1);
#pragma unroll
      for (int nd = 0; nd < 8; ++nd) {
        int r = nd * 16 + l15;
        short8 v0 = *(short8*)&Vp[r * 64 + ((lg ^ (r & 7)) * 8)];
        short8 v1 = *(short8*)&Vp[r * 64 + (((lg + 4) ^ (r & 7)) * 8)];
        o[nd] = __builtin_amdgcn_mfma_f32_16x16x32_bf16(pa0, v0, o[nd], 0, 0, 0);
        o[nd] = __builtin_amdgcn_mfma_f32_16x16x32_bf16(pa1, v1, o[nd], 0, 0, 0);
      }
      __builtin_amdgcn_s_setprio(0);
    }
    __builtin_amdgcn_s_barrier();
  }

  if (l < 16) { Mlds[w * 16 + l] = m_r; Llds[w * 16 + l] = l_r; }
  __syncthreads();
  float* Ob = (float*)KV;
#pragma unroll
  for (int nd = 0; nd < 8; ++nd)
#pragma unroll
    for (int j = 0; j < 4; ++j)
      Ob[w * 2112 + (lg * 4 + j) * 132 + nd * 16 + l15] = o[nd][j];
  __syncthreads();
  {
    const int w0 = qsub * 2, w1 = qsub * 2 + 1;
    float al0[4], al1[4], Lt[4];
#pragma unroll
    for (int j = 0; j < 4; ++j) {
      int q2 = lg * 4 + j;
      float ma = Mlds[w0 * 16 + q2], mb = Mlds[w1 * 16 + q2];
      float M = fmaxf(ma, mb);
      al0[j] = exp2f(ma - M); al1[j] = exp2f(mb - M);
      Lt[j] = al0[j] * Llds[w0 * 16 + q2] + al1[j] * Llds[w1 * 16 + q2];
    }
#pragma unroll
    for (int t2 = 0; t2 < 4; ++t2) {
      int nd = ksp * 4 + t2;
#pragma unroll
      for (int j = 0; j < 4; ++j) {
        int q2 = lg * 4 + j;
        float acc2 = al0[j] * Ob[w0 * 2112 + q2 * 132 + nd * 16 + l15]
                   + al1[j] * Ob[w1 * 2112 + q2 * 132 + nd * 16 + l15];
        out[(bbase + qb0 + q2) * DH + nd * 16 + l15] = acc2 / Lt[j];
      }
    }
  }
}

extern "C" void kernel_launch(void* const* d_in, const int* in_sizes, int n_in,
                              void* d_out, int out_size, void* d_ws, size_t ws_size,
                              hipStream_t stream) {
  const float* x    = (const float*)d_in[0];
  const float* wq   = (const float*)d_in[1];
  const float* bq   = (const float*)d_in[2];
  const float* wk   = (const float*)d_in[3];
  const float* bk   = (const float*)d_in[4];
  const float* wv   = (const float*)d_in[5];
  const float* bv   = (const float*)d_in[6];
  const float* sing = (const float*)d_in[7];
  const float* cosg = (const float*)d_in[8];
  float* out = (float*)d_out;

  char* ws = (char*)d_ws;
  unsigned short* wb = (unsigned short*)ws;                        // 3,145,728 B
  float* biasws = (float*)(ws + 3145728);                          // 1,536 B
  unsigned short* qb = (unsigned short*)(ws + 3147264);            // 4 MB
  unsigned short* kb = (unsigned short*)(ws + 3147264 + 4194304);  // 4 MB
  unsigned short* vt = (unsigned short*)(ws + 3147264 + 2 * 4194304);  // 4 MB (V^T)
  // total ws use: ~15.7 MB

  cast_w_kernel<<<768, 256, 0, stream>>>(wq, wk, wv, bq, bk, bv, wb, biasws);
  gemm_qkv_rope<<<1536, 128, 0, stream>>>(x, wb, biasws, sing, cosg, qb, kb, vt);
  attn_kernel<<<512, 256, 0, stream>>>(qb, kb, vt, out);
}

// Round 17
// 177.052 us; speedup vs baseline: 2.9023x; 2.9023x over previous
//
#include <hip/hip_runtime.h>
#include <hip/hip_bf16.h>
#include <float.h>
#include <math.h>

typedef float f32x4 __attribute__((ext_vector_type(4)));
typedef short short8 __attribute__((ext_vector_type(8)));
typedef unsigned int uint32;

#define NB 4
#define SQ 4096
#define DM 4096
#define DH 128
#define LOG2E 1.44269504088896f
#define SCALE 0.0883883476483184f   // 1/sqrt(128)
#define SCL2 (SCALE * LOG2E)        // fold into log2 domain

__device__ __forceinline__ unsigned short f2bf(float f) {
  union { float f; unsigned u; } x; x.f = f;
  unsigned r = x.u + 0x7FFFu + ((x.u >> 16) & 1u);
  return (unsigned short)(r >> 16);
}

__device__ __forceinline__ uint2 cvt4(float4 f) {
  uint2 u;
  asm("v_cvt_pk_bf16_f32 %0, %1, %2" : "=v"(u.x) : "v"(f.x), "v"(f.y));
  asm("v_cvt_pk_bf16_f32 %0, %1, %2" : "=v"(u.y) : "v"(f.z), "v"(f.w));
  return u;
}

#define GLD16(g, l) __builtin_amdgcn_global_load_lds( \
    (const __attribute__((address_space(1))) void*)(g), \
    (__attribute__((address_space(3))) void*)(l), 16, 0, 0)

// ---------------- kernel 1: pack weights (bf16) + bias (f32) ----------------
__global__ void cast_w_kernel(const float* __restrict__ wq, const float* __restrict__ wk,
                              const float* __restrict__ wv, const float* __restrict__ bq,
                              const float* __restrict__ bk, const float* __restrict__ bv,
                              unsigned short* __restrict__ wb, float* __restrict__ biasws) {
  int t = blockIdx.x * 256 + threadIdx.x;  // 0..196607, each handles 8 elems
  int base = t * 8;
  int n = base >> 12;       // output row 0..383 (q:0-127, k:128-255, v:256-383)
  int d = base & 4095;
  const float* src = (n < 128) ? (wq + (size_t)n * DM)
                   : (n < 256) ? (wk + (size_t)(n - 128) * DM)
                               : (wv + (size_t)(n - 256) * DM);
  float4 f0 = *(const float4*)(src + d);
  float4 f1 = *(const float4*)(src + d + 4);
  short8 v;
  v[0] = (short)f2bf(f0.x); v[1] = (short)f2bf(f0.y);
  v[2] = (short)f2bf(f0.z); v[3] = (short)f2bf(f0.w);
  v[4] = (short)f2bf(f1.x); v[5] = (short)f2bf(f1.y);
  v[6] = (short)f2bf(f1.z); v[7] = (short)f2bf(f1.w);
  *(short8*)(wb + base) = v;
  if (t < 384) biasws[t] = (t < 128) ? bq[t] : (t < 256) ? bk[t - 128] : bv[t - 256];
}

// ---------------- kernel 2: fused QKV GEMM + bias + RoPE (+ V^T store) ------
// R8 structure (best measured: 150 us) -- frozen after 8 falsified rewrites
// (2-phase, deep-prefetch, counted-vmcnt variants, reg-stream x2, small-block
// hi-occ, split-K, pure-DMA split-K). BM=64, BN=128 (one head per block),
// BK=64, 4 waves (2m x 2n), 3 blocks/CU, counted-vmcnt pipeline, one raw
// s_barrier/iter. head==2 epilogue writes V TRANSPOSED directly.
__global__ __launch_bounds__(256) void gemm_qkv_rope(
    const float* __restrict__ x, const unsigned short* __restrict__ wb,
    const float* __restrict__ biasws, const float* __restrict__ sing,
    const float* __restrict__ cosg, unsigned short* __restrict__ qb,
    unsigned short* __restrict__ kb, unsigned short* __restrict__ vt) {
  __shared__ __align__(16) short Alds[2 * 64 * 64];
  __shared__ __align__(16) short Blds[2 * 128 * 64];
  const int tid = threadIdx.x;
  const int l = tid & 63, w = tid >> 6;
  const int wm = w >> 1, wn = w & 1;
  const int l15 = l & 15, lg = l >> 4;
  const int bid = blockIdx.x;
  const int xcd = bid & 7, j = bid >> 3;
  const int mloc = j / 3, head = j - mloc * 3;
  const int m0 = (xcd * 32 + mloc) * 64;
  f32x4 acc[2][4] = {};
  const int ar0 = tid >> 4, ac4 = (tid & 15) * 4;
  const float* xsrc = x + (size_t)(m0 + ar0) * DM + ac4;
  const int achunk = (tid & 15) >> 1, ahalf = tid & 1;
  const int brow_ = tid >> 3, bchunk = tid & 7;
  const unsigned short* wbh = wb + (size_t)head * 128 * DM;
  float4 a00, a01, a02, a03, a10, a11, a12, a13;
  {
#pragma unroll
    for (int i = 0; i < 4; ++i) {
      float4 f = *(const float4*)(xsrc + (size_t)i * 16 * DM);
      int row = ar0 + i * 16;
      *(uint2*)&Alds[row * 64 + ((achunk ^ (row & 7)) * 8) + ahalf * 4] = cvt4(f);
    }
#pragma unroll
    for (int i = 0; i < 4; ++i) {
      int row = i * 32 + brow_;
      int slot = i * 256 + tid;
      GLD16(wbh + (size_t)row * DM + ((bchunk ^ (row & 7)) * 8), (char*)Blds + slot * 16);
    }
    a00 = *(const float4*)(xsrc + 64);
    a01 = *(const float4*)(xsrc + (size_t)16 * DM + 64);
    a02 = *(const float4*)(xsrc + (size_t)32 * DM + 64);
    a03 = *(const float4*)(xsrc + (size_t)48 * DM + 64);
  }
  auto giter = [&](int t, int CUR,
                   float4& n0, float4& n1, float4& n2, float4& n3,
                   float4& f0, float4& f1, float4& f2, float4& f3) {
    asm volatile("s_waitcnt vmcnt(4) lgkmcnt(0)" ::: "memory");
    __builtin_amdgcn_sched_barrier(0);
    __builtin_amdgcn_s_barrier();
    __builtin_amdgcn_sched_barrier(0);
    const int kB = (t + 1) * 64;
    char* bdst = (char*)Blds + (CUR ^ 1) * 16384;
#pragma unroll
    for (int i = 0; i < 4; ++i) {
      int row = i * 32 + brow_;
      int slot = i * 256 + tid;
      GLD16(wbh + (size_t)row * DM + kB + ((bchunk ^ (row & 7)) * 8), bdst + slot * 16);
    }
    __builtin_amdgcn_sched_barrier(0);
    const int kF = (t < 62) ? (t + 2) * 64 : 0;
    f0 = *(const float4*)(xsrc + kF);
    f1 = *(const float4*)(xsrc + (size_t)16 * DM + kF);
    f2 = *(const float4*)(xsrc + (size_t)32 * DM + kF);
    f3 = *(const float4*)(xsrc + (size_t)48 * DM + kF);
#pragma unroll
    for (int kc = 0; kc < 2; ++kc) {
      short8 af[2], bfr[4];
#pragma unroll
      for (int mi = 0; mi < 2; ++mi) {
        int r = wm * 32 + mi * 16 + l15;
        af[mi] = *(short8*)&Alds[CUR * 4096 + r * 64 + ((kc * 32 + lg * 8) ^ ((r & 7) << 3))];
      }
#pragma unroll
      for (int ni = 0; ni < 4; ++ni) {
        int r = wn * 64 + ni * 16 + l15;
        bfr[ni] = *(short8*)&Blds[CUR * 8192 + r * 64 + ((kc * 32 + lg * 8) ^ ((r & 7) << 3))];
      }
#pragma unroll
      for (int mi = 0; mi < 2; ++mi)
#pragma unroll
        for (int ni = 0; ni < 4; ++ni)
          acc[mi][ni] = __builtin_amdgcn_mfma_f32_16x16x32_bf16(af[mi], bfr[ni], acc[mi][ni], 0, 0, 0);
    }
    short* Adst = &Alds[(CUR ^ 1) * 4096];
    int r0 = ar0, r1 = ar0 + 16, r2 = ar0 + 32, r3 = ar0 + 48;
    *(uint2*)&Adst[r0 * 64 + ((achunk ^ (r0 & 7)) * 8) + ahalf * 4] = cvt4(n0);
    *(uint2*)&Adst[r1 * 64 + ((achunk ^ (r1 & 7)) * 8) + ahalf * 4] = cvt4(n1);
    *(uint2*)&Adst[r2 * 64 + ((achunk ^ (r2 & 7)) * 8) + ahalf * 4] = cvt4(n2);
    *(uint2*)&Adst[r3 * 64 + ((achunk ^ (r3 & 7)) * 8) + ahalf * 4] = cvt4(n3);
  };
#pragma unroll 1
  for (int t = 0; t < 62; t += 2) {
    giter(t, 0, a00, a01, a02, a03, a10, a11, a12, a13);
    giter(t + 1, 1, a10, a11, a12, a13, a00, a01, a02, a03);
  }
  giter(62, 0, a00, a01, a02, a03, a10, a11, a12, a13);
  {
    asm volatile("s_waitcnt vmcnt(0) lgkmcnt(0)" ::: "memory");
    __builtin_amdgcn_sched_barrier(0);
    __builtin_amdgcn_s_barrier();
    __builtin_amdgcn_sched_barrier(0);
#pragma unroll
    for (int kc = 0; kc < 2; ++kc) {
      short8 af[2], bfr[4];
#pragma unroll
      for (int mi = 0; mi < 2; ++mi) {
        int r = wm * 32 + mi * 16 + l15;
        af[mi] = *(short8*)&Alds[4096 + r * 64 + ((kc * 32 + lg * 8) ^ ((r & 7) << 3))];
      }
#pragma unroll
      for (int ni = 0; ni < 4; ++ni) {
        int r = wn * 64 + ni * 16 + l15;
        bfr[ni] = *(short8*)&Blds[8192 + r * 64 + ((kc * 32 + lg * 8) ^ ((r & 7) << 3))];
      }
#pragma unroll
      for (int mi = 0; mi < 2; ++mi)
#pragma unroll
        for (int ni = 0; ni < 4; ++ni)
          acc[mi][ni] = __builtin_amdgcn_mfma_f32_16x16x32_bf16(af[mi], bfr[ni], acc[mi][ni], 0, 0, 0);
    }
  }
  if (head == 2) {
    unsigned short* vtb = vt + (size_t)(m0 >> 12) * DH * SQ;
    const int srow = (m0 & (SQ - 1)) + wm * 32;
#pragma unroll
    for (int mi = 0; mi < 2; ++mi)
#pragma unroll
      for (int ni = 0; ni < 4; ++ni) {
        int h = wn * 64 + ni * 16 + l15;
        float bias = biasws[256 + h];
        f32x4 a = acc[mi][ni];
        float4 f;
        f.x = a[0] + bias; f.y = a[1] + bias; f.z = a[2] + bias; f.w = a[3] + bias;
        *(uint2*)&vtb[(size_t)h * SQ + srow + mi * 16 + lg * 4] = cvt4(f);
      }
  } else {
    unsigned short* dst = (head == 0) ? qb : kb;
#pragma unroll
    for (int mi = 0; mi < 2; ++mi)
#pragma unroll
      for (int ni = 0; ni < 4; ++ni) {
        int h = wn * 64 + ni * 16 + l15;
        float bias = biasws[head * 128 + h];
        f32x4 a = acc[mi][ni];
#pragma unroll
        for (int j2 = 0; j2 < 4; ++j2) {
          int row = m0 + wm * 32 + mi * 16 + lg * 4 + j2;
          float val = a[j2] + bias;
          int s = row & (SQ - 1);
          float cs = cosg[s * DH + h];
          float sn = sing[s * DH + h];
          float pr = __shfl_xor(val, 1, 64);
          float sw = (l & 1) ? val : pr;
          val = val * cs + sw * sn;
          dst[(size_t)row * DH + h] = f2bf(val);
        }
      }
  }
}

// ---------------- kernel 3: causal flash attention, QBLK=32 ----------------
// (R14 -- measured ~20us) 512 blocks x 4 waves: wave = qsub x ksplit. Each
// ksplit pair stages K[64][128] + V^T[128][64] into LDS via GLD16; both qsub
// waves consume it. Swapped QK^T, in-lane softmax, log2 domain, defer-max.
// 2-way end merge (Obuf aliases KV region after loop).
__global__ __launch_bounds__(256) void attn_kernel(
    const unsigned short* __restrict__ qb, const unsigned short* __restrict__ kb,
    const unsigned short* __restrict__ vt, float* __restrict__ out) {
  __shared__ __align__(16) short KV[4 * 8192];        // 64 KB
  __shared__ __align__(16) short Plds4[4 * 1152];     // 9 KB
  __shared__ __align__(16) float Mlds[64];
  __shared__ __align__(16) float Llds[64];
  __shared__ __align__(16) float Clds[64];
  const int tid = threadIdx.x;
  const int w = tid >> 6, l = tid & 63;
  const int qsub = w >> 1, ksp = w & 1;
  const int l15 = l & 15, lg = l >> 4;

  const int bi = blockIdx.x;
  const int slot = bi & 7, p5 = slot & 1, batch = slot >> 1;
  const int a = bi >> 3;  // 0..63
  const int t = (a & 1) ? (127 - p5 * 32 - (a >> 1)) : (p5 * 32 + (a >> 1));
  const int q0 = t * 32;
  const int qb0 = q0 + qsub * 16;
  const size_t bbase = (size_t)batch * SQ;
  const unsigned short* Kb = kb + bbase * DH;
  const unsigned short* Vtb = vt + (size_t)batch * DH * SQ;

  short* Kp = KV + ksp * 8192;            // [64][128] bf16, chunk^(row&15)
  short* Vp = KV + 16384 + ksp * 8192;    // [128][64] bf16, chunk^(row&7)
  short* Pw = Plds4 + w * 1152;           // [16][72]

  const int ti = qsub * 64 + l;
  const int krow_ = ti >> 4, kc_ = ti & 15;
  const int vrow_ = ti >> 3, vc_ = ti & 7;

  short8 qf[4];
  {
    const unsigned short* qp = qb + (bbase + qb0 + l15) * DH + lg * 8;
#pragma unroll
    for (int kcd = 0; kcd < 4; ++kcd) qf[kcd] = *(const short8*)(qp + kcd * 32);
  }

  const int nsteps = (q0 + 32 + 63) >> 6;
  const int nsteps_w = (qb0 + 16 + 63) >> 6;
  const int max_nit = (nsteps + 1) >> 1;

  float m_r = -INFINITY, l_r = 0.f;
  f32x4 o[8] = {};

  for (int it = 0; it < max_nit; ++it) {
    const int st = it * 2 + ksp;
    const int kv0 = st * 64;
    if (st < nsteps) {
#pragma unroll
      for (int i = 0; i < 8; ++i) {
        int row = i * 8 + krow_;
        GLD16(Kb + (size_t)(kv0 + row) * DH + ((kc_ ^ (row & 15)) * 8),
              (char*)Kp + (i * 128 + ti) * 16);
      }
#pragma unroll
      for (int i = 0; i < 8; ++i) {
        int row = i * 16 + vrow_;
        GLD16(Vtb + (size_t)row * SQ + kv0 + ((vc_ ^ (row & 7)) * 8),
              (char*)Vp + (i * 128 + ti) * 16);
      }
    }
    asm volatile("s_waitcnt vmcnt(0)" ::: "memory");
    __builtin_amdgcn_s_barrier();

    if (st < nsteps_w) {
      f32x4 sf[4] = {};
      __builtin_amdgcn_s_setprio(1);
#pragma unroll
      for (int kcd = 0; kcd < 4; ++kcd)
#pragma unroll
        for (int ni = 0; ni < 4; ++ni) {
          int r = ni * 16 + l15;
          short8 kf = *(short8*)&Kp[r * 128 + (((kcd * 4 + lg) ^ (r & 15)) * 8)];
          sf[ni] = __builtin_amdgcn_mfma_f32_16x16x32_bf16(kf, qf[kcd], sf[ni], 0, 0, 0);
        }
      __builtin_amdgcn_s_setprio(0);

      float s[4][4];
      if (st == nsteps_w - 1) {
#pragma unroll
        for (int ni = 0; ni < 4; ++ni)
#pragma unroll
          for (int j = 0; j < 4; ++j) {
            float v = sf[ni][j] * SCL2;
            if (kv0 + ni * 16 + lg * 4 + j > qb0 + l15) v = -FLT_MAX;
            s[ni][j] = v;
          }
      } else {
#pragma unroll
        for (int ni = 0; ni < 4; ++ni)
#pragma unroll
          for (int j = 0; j < 4; ++j) s[ni][j] = sf[ni][j] * SCL2;
      }

      float tmx = s[0][0];
#pragma unroll
      for (int ni = 0; ni < 4; ++ni)
#pragma unroll
        for (int j = 0; j < 4; ++j) tmx = fmaxf(tmx, s[ni][j]);
      tmx = fmaxf(tmx, __shfl_xor(tmx, 16, 64));
      tmx = fmaxf(tmx, __shfl_xor(tmx, 32, 64));

      if (__any(tmx > m_r + 8.0f)) {
        float mnew = fmaxf(m_r, tmx);
        float corr = exp2f(m_r - mnew);
        if (l < 16) Clds[w * 16 + l] = corr;
        l_r *= corr; m_r = mnew;
        f32x4 c4 = *(f32x4*)&Clds[w * 16 + lg * 4];
#pragma unroll
        for (int nd = 0; nd < 8; ++nd)
#pragma unroll
          for (int j = 0; j < 4; ++j) o[nd][j] *= c4[j];
      }

      float rs = 0.f;
      float pp[4][4];
#pragma unroll
      for (int ni = 0; ni < 4; ++ni)
#pragma unroll
        for (int j = 0; j < 4; ++j) {
          pp[ni][j] = exp2f(s[ni][j] - m_r);
          rs += pp[ni][j];
        }
      rs += __shfl_xor(rs, 16, 64);
      rs += __shfl_xor(rs, 32, 64);
      l_r += rs;

#pragma unroll
      for (int ni = 0; ni < 4; ++ni) {
        uint32 lo, hi;
        asm volatile("v_cvt_pk_bf16_f32 %0, %1, %2" : "=v"(lo) : "v"(pp[ni][0]), "v"(pp[ni][1]));
        asm volatile("v_cvt_pk_bf16_f32 %0, %1, %2" : "=v"(hi) : "v"(pp[ni][2]), "v"(pp[ni][3]));
        uint2 u; u.x = lo; u.y = hi;
        *(uint2*)&Pw[l15 * 72 + ni * 16 + lg * 4] = u;
      }
      short8 pa0 = *(short8*)&Pw[l15 * 72 + lg * 8];
      short8 pa1 = *(short8*)&Pw[l15 * 72 + 32 + lg * 8];

      __builtin_amdgcn_s_setprio(1);
#pragma unroll
      for (int nd = 0; nd < 8; ++nd) {
        int r = nd * 16 + l15;
        short8 v0 = *(short8*)&Vp[r * 64 + ((lg ^ (r & 7)) * 8)];
        short8 v1 = *(short8*)&Vp[r * 64 + (((lg + 4) ^ (r & 7)) * 8)];
        o[nd] = __builtin_amdgcn_mfma_f32_16x16x32_bf16(pa0, v0, o[nd], 0, 0, 0);
        o[nd] = __builtin_amdgcn_mfma_f32_16x16x32_bf16(pa1, v1, o[nd], 0, 0, 0);
      }
      __builtin_amdgcn_s_setprio(0);
    }
    __builtin_amdgcn_s_barrier();
  }

  if (l < 16) { Mlds[w * 16 + l] = m_r; Llds[w * 16 + l] = l_r; }
  __syncthreads();
  float* Ob = (float*)KV;
#pragma unroll
  for (int nd = 0; nd < 8; ++nd)
#pragma unroll
    for (int j = 0; j < 4; ++j)
      Ob[w * 2112 + (lg * 4 + j) * 132 + nd * 16 + l15] = o[nd][j];
  __syncthreads();
  {
    const int w0 = qsub * 2, w1 = qsub * 2 + 1;
    float al0[4], al1[4], Lt[4];
#pragma unroll
    for (int j = 0; j < 4; ++j) {
      int q2 = lg * 4 + j;
      float ma = Mlds[w0 * 16 + q2], mb = Mlds[w1 * 16 + q2];
      float M = fmaxf(ma, mb);
      al0[j] = exp2f(ma - M); al1[j] = exp2f(mb - M);
      Lt[j] = al0[j] * Llds[w0 * 16 + q2] + al1[j] * Llds[w1 * 16 + q2];
    }
#pragma unroll
    for (int t2 = 0; t2 < 4; ++t2) {
      int nd = ksp * 4 + t2;
#pragma unroll
      for (int j = 0; j < 4; ++j) {
        int q2 = lg * 4 + j;
        float acc2 = al0[j] * Ob[w0 * 2112 + q2 * 132 + nd * 16 + l15]
                   + al1[j] * Ob[w1 * 2112 + q2 * 132 + nd * 16 + l15];
        out[(bbase + qb0 + q2) * DH + nd * 16 + l15] = acc2 / Lt[j];
      }
    }
  }
}

extern "C" void kernel_launch(void* const* d_in, const int* in_sizes, int n_in,
                              void* d_out, int out_size, void* d_ws, size_t ws_size,
                              hipStream_t stream) {
  const float* x    = (const float*)d_in[0];
  const float* wq   = (const float*)d_in[1];
  const float* bq   = (const float*)d_in[2];
  const float* wk   = (const float*)d_in[3];
  const float* bk   = (const float*)d_in[4];
  const float* wv   = (const float*)d_in[5];
  const float* bv   = (const float*)d_in[6];
  const float* sing = (const float*)d_in[7];
  const float* cosg = (const float*)d_in[8];
  float* out = (float*)d_out;

  char* ws = (char*)d_ws;
  unsigned short* wb = (unsigned short*)ws;                        // 3,145,728 B
  float* biasws = (float*)(ws + 3145728);                          // 1,536 B
  unsigned short* qb = (unsigned short*)(ws + 3147264);            // 4 MB
  unsigned short* kb = (unsigned short*)(ws + 3147264 + 4194304);  // 4 MB
  unsigned short* vt = (unsigned short*)(ws + 3147264 + 2 * 4194304);  // 4 MB (V^T)
  // total ws use: ~15.7 MB

  cast_w_kernel<<<768, 256, 0, stream>>>(wq, wk, wv, bq, bk, bv, wb, biasws);
  gemm_qkv_rope<<<768, 256, 0, stream>>>(x, wb, biasws, sing, cosg, qb, kb, vt);
  attn_kernel<<<512, 256, 0, stream>>>(qb, kb, vt, out);
}

// Round 18
// 176.559 us; speedup vs baseline: 2.9104x; 1.0028x over previous
//
#include <hip/hip_runtime.h>
#include <hip/hip_bf16.h>
#include <float.h>
#include <math.h>

typedef float f32x4 __attribute__((ext_vector_type(4)));
typedef short short8 __attribute__((ext_vector_type(8)));
typedef unsigned int uint32;

#define NB 4
#define SQ 4096
#define DM 4096
#define DH 128
#define LOG2E 1.44269504088896f
#define SCALE 0.0883883476483184f   // 1/sqrt(128)
#define SCL2 (SCALE * LOG2E)        // fold into log2 domain

__device__ __forceinline__ unsigned short f2bf(float f) {
  union { float f; unsigned u; } x; x.f = f;
  unsigned r = x.u + 0x7FFFu + ((x.u >> 16) & 1u);
  return (unsigned short)(r >> 16);
}

__device__ __forceinline__ uint2 cvt4(float4 f) {
  uint2 u;
  asm("v_cvt_pk_bf16_f32 %0, %1, %2" : "=v"(u.x) : "v"(f.x), "v"(f.y));
  asm("v_cvt_pk_bf16_f32 %0, %1, %2" : "=v"(u.y) : "v"(f.z), "v"(f.w));
  return u;
}

#define GLD16(g, l) __builtin_amdgcn_global_load_lds( \
    (const __attribute__((address_space(1))) void*)(g), \
    (__attribute__((address_space(3))) void*)(l), 16, 0, 0)

// ---------------- kernel 1: pack weights (bf16) + bias (f32) ----------------
__global__ void cast_w_kernel(const float* __restrict__ wq, const float* __restrict__ wk,
                              const float* __restrict__ wv, const float* __restrict__ bq,
                              const float* __restrict__ bk, const float* __restrict__ bv,
                              unsigned short* __restrict__ wb, float* __restrict__ biasws) {
  int t = blockIdx.x * 256 + threadIdx.x;  // 0..196607, each handles 8 elems
  int base = t * 8;
  int n = base >> 12;       // output row 0..383 (q:0-127, k:128-255, v:256-383)
  int d = base & 4095;
  const float* src = (n < 128) ? (wq + (size_t)n * DM)
                   : (n < 256) ? (wk + (size_t)(n - 128) * DM)
                               : (wv + (size_t)(n - 256) * DM);
  float4 f0 = *(const float4*)(src + d);
  float4 f1 = *(const float4*)(src + d + 4);
  short8 v;
  v[0] = (short)f2bf(f0.x); v[1] = (short)f2bf(f0.y);
  v[2] = (short)f2bf(f0.z); v[3] = (short)f2bf(f0.w);
  v[4] = (short)f2bf(f1.x); v[5] = (short)f2bf(f1.y);
  v[6] = (short)f2bf(f1.z); v[7] = (short)f2bf(f1.w);
  *(short8*)(wb + base) = v;
  if (t < 384) biasws[t] = (t < 128) ? bq[t] : (t < 256) ? bk[t - 128] : bv[t - 256];
}

// ---------------- kernel 2: fused QKV GEMM + bias + RoPE (+ V^T store) ------
// R8 structure (best measured: 150 us) -- K-loop FROZEN after 8 falsified
// rewrites. BM=64, BN=128 (one head per block), BK=64, 4 waves (2m x 2n),
// 3 blocks/CU, counted-vmcnt pipeline, one raw s_barrier/iter.
// head==2 epilogue writes V TRANSPOSED directly. NEW (R18): Q/K epilogue
// vectorized -- RoPE'd tile round-trips LDS (reuse Blds, [64][136] shorts,
// 2-way-conflict-only) then 4x short8 coalesced stores per thread (was 32
// scalar 2B stores -> issue-bound tail).
__global__ __launch_bounds__(256) void gemm_qkv_rope(
    const float* __restrict__ x, const unsigned short* __restrict__ wb,
    const float* __restrict__ biasws, const float* __restrict__ sing,
    const float* __restrict__ cosg, unsigned short* __restrict__ qb,
    unsigned short* __restrict__ kb, unsigned short* __restrict__ vt) {
  __shared__ __align__(16) short Alds[2 * 64 * 64];
  __shared__ __align__(16) short Blds[2 * 128 * 64];
  const int tid = threadIdx.x;
  const int l = tid & 63, w = tid >> 6;
  const int wm = w >> 1, wn = w & 1;
  const int l15 = l & 15, lg = l >> 4;
  const int bid = blockIdx.x;
  const int xcd = bid & 7, j = bid >> 3;
  const int mloc = j / 3, head = j - mloc * 3;
  const int m0 = (xcd * 32 + mloc) * 64;
  f32x4 acc[2][4] = {};
  const int ar0 = tid >> 4, ac4 = (tid & 15) * 4;
  const float* xsrc = x + (size_t)(m0 + ar0) * DM + ac4;
  const int achunk = (tid & 15) >> 1, ahalf = tid & 1;
  const int brow_ = tid >> 3, bchunk = tid & 7;
  const unsigned short* wbh = wb + (size_t)head * 128 * DM;
  float4 a00, a01, a02, a03, a10, a11, a12, a13;
  {
#pragma unroll
    for (int i = 0; i < 4; ++i) {
      float4 f = *(const float4*)(xsrc + (size_t)i * 16 * DM);
      int row = ar0 + i * 16;
      *(uint2*)&Alds[row * 64 + ((achunk ^ (row & 7)) * 8) + ahalf * 4] = cvt4(f);
    }
#pragma unroll
    for (int i = 0; i < 4; ++i) {
      int row = i * 32 + brow_;
      int slot = i * 256 + tid;
      GLD16(wbh + (size_t)row * DM + ((bchunk ^ (row & 7)) * 8), (char*)Blds + slot * 16);
    }
    a00 = *(const float4*)(xsrc + 64);
    a01 = *(const float4*)(xsrc + (size_t)16 * DM + 64);
    a02 = *(const float4*)(xsrc + (size_t)32 * DM + 64);
    a03 = *(const float4*)(xsrc + (size_t)48 * DM + 64);
  }
  auto giter = [&](int t, int CUR,
                   float4& n0, float4& n1, float4& n2, float4& n3,
                   float4& f0, float4& f1, float4& f2, float4& f3) {
    asm volatile("s_waitcnt vmcnt(4) lgkmcnt(0)" ::: "memory");
    __builtin_amdgcn_sched_barrier(0);
    __builtin_amdgcn_s_barrier();
    __builtin_amdgcn_sched_barrier(0);
    const int kB = (t + 1) * 64;
    char* bdst = (char*)Blds + (CUR ^ 1) * 16384;
#pragma unroll
    for (int i = 0; i < 4; ++i) {
      int row = i * 32 + brow_;
      int slot = i * 256 + tid;
      GLD16(wbh + (size_t)row * DM + kB + ((bchunk ^ (row & 7)) * 8), bdst + slot * 16);
    }
    __builtin_amdgcn_sched_barrier(0);
    const int kF = (t < 62) ? (t + 2) * 64 : 0;
    f0 = *(const float4*)(xsrc + kF);
    f1 = *(const float4*)(xsrc + (size_t)16 * DM + kF);
    f2 = *(const float4*)(xsrc + (size_t)32 * DM + kF);
    f3 = *(const float4*)(xsrc + (size_t)48 * DM + kF);
#pragma unroll
    for (int kc = 0; kc < 2; ++kc) {
      short8 af[2], bfr[4];
#pragma unroll
      for (int mi = 0; mi < 2; ++mi) {
        int r = wm * 32 + mi * 16 + l15;
        af[mi] = *(short8*)&Alds[CUR * 4096 + r * 64 + ((kc * 32 + lg * 8) ^ ((r & 7) << 3))];
      }
#pragma unroll
      for (int ni = 0; ni < 4; ++ni) {
        int r = wn * 64 + ni * 16 + l15;
        bfr[ni] = *(short8*)&Blds[CUR * 8192 + r * 64 + ((kc * 32 + lg * 8) ^ ((r & 7) << 3))];
      }
#pragma unroll
      for (int mi = 0; mi < 2; ++mi)
#pragma unroll
        for (int ni = 0; ni < 4; ++ni)
          acc[mi][ni] = __builtin_amdgcn_mfma_f32_16x16x32_bf16(af[mi], bfr[ni], acc[mi][ni], 0, 0, 0);
    }
    short* Adst = &Alds[(CUR ^ 1) * 4096];
    int r0 = ar0, r1 = ar0 + 16, r2 = ar0 + 32, r3 = ar0 + 48;
    *(uint2*)&Adst[r0 * 64 + ((achunk ^ (r0 & 7)) * 8) + ahalf * 4] = cvt4(n0);
    *(uint2*)&Adst[r1 * 64 + ((achunk ^ (r1 & 7)) * 8) + ahalf * 4] = cvt4(n1);
    *(uint2*)&Adst[r2 * 64 + ((achunk ^ (r2 & 7)) * 8) + ahalf * 4] = cvt4(n2);
    *(uint2*)&Adst[r3 * 64 + ((achunk ^ (r3 & 7)) * 8) + ahalf * 4] = cvt4(n3);
  };
#pragma unroll 1
  for (int t = 0; t < 62; t += 2) {
    giter(t, 0, a00, a01, a02, a03, a10, a11, a12, a13);
    giter(t + 1, 1, a10, a11, a12, a13, a00, a01, a02, a03);
  }
  giter(62, 0, a00, a01, a02, a03, a10, a11, a12, a13);
  {
    asm volatile("s_waitcnt vmcnt(0) lgkmcnt(0)" ::: "memory");
    __builtin_amdgcn_sched_barrier(0);
    __builtin_amdgcn_s_barrier();
    __builtin_amdgcn_sched_barrier(0);
#pragma unroll
    for (int kc = 0; kc < 2; ++kc) {
      short8 af[2], bfr[4];
#pragma unroll
      for (int mi = 0; mi < 2; ++mi) {
        int r = wm * 32 + mi * 16 + l15;
        af[mi] = *(short8*)&Alds[4096 + r * 64 + ((kc * 32 + lg * 8) ^ ((r & 7) << 3))];
      }
#pragma unroll
      for (int ni = 0; ni < 4; ++ni) {
        int r = wn * 64 + ni * 16 + l15;
        bfr[ni] = *(short8*)&Blds[8192 + r * 64 + ((kc * 32 + lg * 8) ^ ((r & 7) << 3))];
      }
#pragma unroll
      for (int mi = 0; mi < 2; ++mi)
#pragma unroll
        for (int ni = 0; ni < 4; ++ni)
          acc[mi][ni] = __builtin_amdgcn_mfma_f32_16x16x32_bf16(af[mi], bfr[ni], acc[mi][ni], 0, 0, 0);
    }
  }
  if (head == 2) {
    unsigned short* vtb = vt + (size_t)(m0 >> 12) * DH * SQ;
    const int srow = (m0 & (SQ - 1)) + wm * 32;
#pragma unroll
    for (int mi = 0; mi < 2; ++mi)
#pragma unroll
      for (int ni = 0; ni < 4; ++ni) {
        int h = wn * 64 + ni * 16 + l15;
        float bias = biasws[256 + h];
        f32x4 a = acc[mi][ni];
        float4 f;
        f.x = a[0] + bias; f.y = a[1] + bias; f.z = a[2] + bias; f.w = a[3] + bias;
        *(uint2*)&vtb[(size_t)h * SQ + srow + mi * 16 + lg * 4] = cvt4(f);
      }
  } else {
    unsigned short* dst = (head == 0) ? qb : kb;
    // vectorized store: RoPE'd vals -> LDS E[64][136] (reuse Blds) -> short8
    short* E = Blds;
    __syncthreads();   // all waves done with final-tile ds_reads (E overlaps Blds[8192..])
#pragma unroll
    for (int mi = 0; mi < 2; ++mi)
#pragma unroll
      for (int ni = 0; ni < 4; ++ni) {
        int h = wn * 64 + ni * 16 + l15;
        float bias = biasws[head * 128 + h];
        f32x4 a = acc[mi][ni];
#pragma unroll
        for (int j2 = 0; j2 < 4; ++j2) {
          int rloc = wm * 32 + mi * 16 + lg * 4 + j2;   // block-local row 0..63
          float val = a[j2] + bias;
          // reference RoPE: out[h] = v[h]*cos[h] + v_sw[h]*sin[h],
          // v_sw[2i] = v_sw[2i+1] = v[2i+1] (odd element, repeated)
          int s = (m0 + rloc) & (SQ - 1);
          float cs = cosg[s * DH + h];
          float sn = sing[s * DH + h];
          float pr = __shfl_xor(val, 1, 64);      // partner col h^1 (same row)
          float sw = (l & 1) ? val : pr;          // odd h: self; even h: h+1
          val = val * cs + sw * sn;
          E[rloc * 136 + h] = (short)f2bf(val);
        }
      }
    __syncthreads();
    {
      const int rloc = tid >> 2, hb4 = (tid & 3) * 32;  // wave = contiguous 4KB band
#pragma unroll
      for (int i = 0; i < 4; ++i) {
        short8 v8 = *(short8*)&E[rloc * 136 + hb4 + i * 8];
        *(short8*)&dst[(size_t)(m0 + rloc) * DH + hb4 + i * 8] = v8;
      }
    }
  }
}

// ---------------- kernel 3: causal flash attention, QBLK=32 ----------------
// (R14 -- measured ~20us, ~75% of L2 BW ceiling) 512 blocks x 4 waves:
// wave = qsub x ksplit. Each ksplit pair stages K[64][128] + V^T[128][64]
// into LDS via GLD16; both qsub waves consume it. Swapped QK^T, in-lane
// softmax, log2 domain, defer-max. 2-way end merge (Obuf aliases KV region).
__global__ __launch_bounds__(256) void attn_kernel(
    const unsigned short* __restrict__ qb, const unsigned short* __restrict__ kb,
    const unsigned short* __restrict__ vt, float* __restrict__ out) {
  __shared__ __align__(16) short KV[4 * 8192];        // 64 KB
  __shared__ __align__(16) short Plds4[4 * 1152];     // 9 KB
  __shared__ __align__(16) float Mlds[64];
  __shared__ __align__(16) float Llds[64];
  __shared__ __align__(16) float Clds[64];
  const int tid = threadIdx.x;
  const int w = tid >> 6, l = tid & 63;
  const int qsub = w >> 1, ksp = w & 1;
  const int l15 = l & 15, lg = l >> 4;

  const int bi = blockIdx.x;
  const int slot = bi & 7, p5 = slot & 1, batch = slot >> 1;
  const int a = bi >> 3;  // 0..63
  const int t = (a & 1) ? (127 - p5 * 32 - (a >> 1)) : (p5 * 32 + (a >> 1));
  const int q0 = t * 32;
  const int qb0 = q0 + qsub * 16;
  const size_t bbase = (size_t)batch * SQ;
  const unsigned short* Kb = kb + bbase * DH;
  const unsigned short* Vtb = vt + (size_t)batch * DH * SQ;

  short* Kp = KV + ksp * 8192;            // [64][128] bf16, chunk^(row&15)
  short* Vp = KV + 16384 + ksp * 8192;    // [128][64] bf16, chunk^(row&7)
  short* Pw = Plds4 + w * 1152;           // [16][72]

  const int ti = qsub * 64 + l;
  const int krow_ = ti >> 4, kc_ = ti & 15;
  const int vrow_ = ti >> 3, vc_ = ti & 7;

  short8 qf[4];
  {
    const unsigned short* qp = qb + (bbase + qb0 + l15) * DH + lg * 8;
#pragma unroll
    for (int kcd = 0; kcd < 4; ++kcd) qf[kcd] = *(const short8*)(qp + kcd * 32);
  }

  const int nsteps = (q0 + 32 + 63) >> 6;
  const int nsteps_w = (qb0 + 16 + 63) >> 6;
  const int max_nit = (nsteps + 1) >> 1;

  float m_r = -INFINITY, l_r = 0.f;
  f32x4 o[8] = {};

  for (int it = 0; it < max_nit; ++it) {
    const int st = it * 2 + ksp;
    const int kv0 = st * 64;
    if (st < nsteps) {
#pragma unroll
      for (int i = 0; i < 8; ++i) {
        int row = i * 8 + krow_;
        GLD16(Kb + (size_t)(kv0 + row) * DH + ((kc_ ^ (row & 15)) * 8),
              (char*)Kp + (i * 128 + ti) * 16);
      }
#pragma unroll
      for (int i = 0; i < 8; ++i) {
        int row = i * 16 + vrow_;
        GLD16(Vtb + (size_t)row * SQ + kv0 + ((vc_ ^ (row & 7)) * 8),
              (char*)Vp + (i * 128 + ti) * 16);
      }
    }
    asm volatile("s_waitcnt vmcnt(0)" ::: "memory");
    __builtin_amdgcn_s_barrier();

    if (st < nsteps_w) {
      f32x4 sf[4] = {};
      __builtin_amdgcn_s_setprio(1);
#pragma unroll
      for (int kcd = 0; kcd < 4; ++kcd)
#pragma unroll
        for (int ni = 0; ni < 4; ++ni) {
          int r = ni * 16 + l15;
          short8 kf = *(short8*)&Kp[r * 128 + (((kcd * 4 + lg) ^ (r & 15)) * 8)];
          sf[ni] = __builtin_amdgcn_mfma_f32_16x16x32_bf16(kf, qf[kcd], sf[ni], 0, 0, 0);
        }
      __builtin_amdgcn_s_setprio(0);

      float s[4][4];
      if (st == nsteps_w - 1) {
#pragma unroll
        for (int ni = 0; ni < 4; ++ni)
#pragma unroll
          for (int j = 0; j < 4; ++j) {
            float v = sf[ni][j] * SCL2;
            if (kv0 + ni * 16 + lg * 4 + j > qb0 + l15) v = -FLT_MAX;
            s[ni][j] = v;
          }
      } else {
#pragma unroll
        for (int ni = 0; ni < 4; ++ni)
#pragma unroll
          for (int j = 0; j < 4; ++j) s[ni][j] = sf[ni][j] * SCL2;
      }

      float tmx = s[0][0];
#pragma unroll
      for (int ni = 0; ni < 4; ++ni)
#pragma unroll
        for (int j = 0; j < 4; ++j) tmx = fmaxf(tmx, s[ni][j]);
      tmx = fmaxf(tmx, __shfl_xor(tmx, 16, 64));
      tmx = fmaxf(tmx, __shfl_xor(tmx, 32, 64));

      if (__any(tmx > m_r + 8.0f)) {
        float mnew = fmaxf(m_r, tmx);
        float corr = exp2f(m_r - mnew);
        if (l < 16) Clds[w * 16 + l] = corr;
        l_r *= corr; m_r = mnew;
        f32x4 c4 = *(f32x4*)&Clds[w * 16 + lg * 4];
#pragma unroll
        for (int nd = 0; nd < 8; ++nd)
#pragma unroll
          for (int j = 0; j < 4; ++j) o[nd][j] *= c4[j];
      }

      float rs = 0.f;
      float pp[4][4];
#pragma unroll
      for (int ni = 0; ni < 4; ++ni)
#pragma unroll
        for (int j = 0; j < 4; ++j) {
          pp[ni][j] = exp2f(s[ni][j] - m_r);
          rs += pp[ni][j];
        }
      rs += __shfl_xor(rs, 16, 64);
      rs += __shfl_xor(rs, 32, 64);
      l_r += rs;

#pragma unroll
      for (int ni = 0; ni < 4; ++ni) {
        uint32 lo, hi;
        asm volatile("v_cvt_pk_bf16_f32 %0, %1, %2" : "=v"(lo) : "v"(pp[ni][0]), "v"(pp[ni][1]));
        asm volatile("v_cvt_pk_bf16_f32 %0, %1, %2" : "=v"(hi) : "v"(pp[ni][2]), "v"(pp[ni][3]));
        uint2 u; u.x = lo; u.y = hi;
        *(uint2*)&Pw[l15 * 72 + ni * 16 + lg * 4] = u;
      }
      short8 pa0 = *(short8*)&Pw[l15 * 72 + lg * 8];
      short8 pa1 = *(short8*)&Pw[l15 * 72 + 32 + lg * 8];

      __builtin_amdgcn_s_setprio(1);
#pragma unroll
      for (int nd = 0; nd < 8; ++nd) {
        int r = nd * 16 + l15;
        short8 v0 = *(short8*)&Vp[r * 64 + ((lg ^ (r & 7)) * 8)];
        short8 v1 = *(short8*)&Vp[r * 64 + (((lg + 4) ^ (r & 7)) * 8)];
        o[nd] = __builtin_amdgcn_mfma_f32_16x16x32_bf16(pa0, v0, o[nd], 0, 0, 0);
        o[nd] = __builtin_amdgcn_mfma_f32_16x16x32_bf16(pa1, v1, o[nd], 0, 0, 0);
      }
      __builtin_amdgcn_s_setprio(0);
    }
    __builtin_amdgcn_s_barrier();
  }

  if (l < 16) { Mlds[w * 16 + l] = m_r; Llds[w * 16 + l] = l_r; }
  __syncthreads();
  float* Ob = (float*)KV;
#pragma unroll
  for (int nd = 0; nd < 8; ++nd)
#pragma unroll
    for (int j = 0; j < 4; ++j)
      Ob[w * 2112 + (lg * 4 + j) * 132 + nd * 16 + l15] = o[nd][j];
  __syncthreads();
  {
    const int w0 = qsub * 2, w1 = qsub * 2 + 1;
    float al0[4], al1[4], Lt[4];
#pragma unroll
    for (int j = 0; j < 4; ++j) {
      int q2 = lg * 4 + j;
      float ma = Mlds[w0 * 16 + q2], mb = Mlds[w1 * 16 + q2];
      float M = fmaxf(ma, mb);
      al0[j] = exp2f(ma - M); al1[j] = exp2f(mb - M);
      Lt[j] = al0[j] * Llds[w0 * 16 + q2] + al1[j] * Llds[w1 * 16 + q2];
    }
#pragma unroll
    for (int t2 = 0; t2 < 4; ++t2) {
      int nd = ksp * 4 + t2;
#pragma unroll
      for (int j = 0; j < 4; ++j) {
        int q2 = lg * 4 + j;
        float acc2 = al0[j] * Ob[w0 * 2112 + q2 * 132 + nd * 16 + l15]
                   + al1[j] * Ob[w1 * 2112 + q2 * 132 + nd * 16 + l15];
        out[(bbase + qb0 + q2) * DH + nd * 16 + l15] = acc2 / Lt[j];
      }
    }
  }
}

extern "C" void kernel_launch(void* const* d_in, const int* in_sizes, int n_in,
                              void* d_out, int out_size, void* d_ws, size_t ws_size,
                              hipStream_t stream) {
  const float* x    = (const float*)d_in[0];
  const float* wq   = (const float*)d_in[1];
  const float* bq   = (const float*)d_in[2];
  const float* wk   = (const float*)d_in[3];
  const float* bk   = (const float*)d_in[4];
  const float* wv   = (const float*)d_in[5];
  const float* bv   = (const float*)d_in[6];
  const float* sing = (const float*)d_in[7];
  const float* cosg = (const float*)d_in[8];
  float* out = (float*)d_out;

  char* ws = (char*)d_ws;
  unsigned short* wb = (unsigned short*)ws;                        // 3,145,728 B
  float* biasws = (float*)(ws + 3145728);                          // 1,536 B
  unsigned short* qb = (unsigned short*)(ws + 3147264);            // 4 MB
  unsigned short* kb = (unsigned short*)(ws + 3147264 + 4194304);  // 4 MB
  unsigned short* vt = (unsigned short*)(ws + 3147264 + 2 * 4194304);  // 4 MB (V^T)
  // total ws use: ~15.7 MB

  cast_w_kernel<<<768, 256, 0, stream>>>(wq, wk, wv, bq, bk, bv, wb, biasws);
  gemm_qkv_rope<<<768, 256, 0, stream>>>(x, wb, biasws, sing, cosg, qb, kb, vt);
  attn_kernel<<<512, 256, 0, stream>>>(qb, kb, vt, out);
}